// Round 1
// baseline (2393.922 us; speedup 1.0000x reference)
//
#include <hip/hip_runtime.h>
#include <stdint.h>

#define T_STEPS 512
#define H_DIM   256
#define NBG     16
#define NCG     8
#define BM      16
#define NTHR    512

typedef unsigned short u16;
typedef __attribute__((ext_vector_type(8))) short short8;
typedef __attribute__((ext_vector_type(4))) float f32x4;

__device__ __forceinline__ u16 f2bf(float f) {
    unsigned u = __float_as_uint(f);
    unsigned r = (u + 0x7fffu + ((u >> 16) & 1u)) >> 16;
    return (u16)r;
}
__device__ __forceinline__ float bf2f(u16 h) {
    return __uint_as_float(((unsigned)h) << 16);
}
__device__ __forceinline__ float sigmoid_f(float v) {
    return 1.0f / (1.0f + __expf(-v));
}
__device__ __forceinline__ float tanh_f(float v) {
    float e = __expf(2.0f * v);
    return 1.0f - 2.0f / (e + 1.0f);
}

// Grid: 128 blocks = 16 batch-groups (bg) x 8 col-groups (g).
// Block: 512 threads = 8 waves; wave w owns gate-column tile [16w, 16w+16) of
// this wg's 128 gate columns (col c = jloc*4 + gate, jloc in [0,32)).
// W_hh slice lives in REGISTERS as bf16 hi/lo split for all 512 steps.
// h exchanged between the 8 col-groups of a batch-group via global memory
// (bf16 hi/lo pair) + per-(t,bg) release/acquire counters.
__global__ void __launch_bounds__(NTHR)
lstm_pipe_kernel(const float* __restrict__ x,
                 const float* __restrict__ W_ih,
                 const float* __restrict__ W_hh,
                 const float* __restrict__ b_ih,
                 const float* __restrict__ b_hh,
                 const float* __restrict__ W_lin,
                 const float* __restrict__ b_lin,
                 float* __restrict__ out,
                 u16* __restrict__ hb_hi,
                 u16* __restrict__ hb_lo,
                 unsigned* __restrict__ cnt)
{
    const int tid  = threadIdx.x;
    const int bg   = blockIdx.x & (NBG - 1);
    const int g    = blockIdx.x >> 4;
    const int wave = tid >> 6;
    const int lane = tid & 63;
    const int cl   = lane & 15;
    const int kgrp = lane >> 4;

    __shared__ __align__(16) u16 HShi[BM * H_DIM];   // staged h_{t-1} hi, swizzled
    __shared__ __align__(16) u16 HSlo[BM * H_DIM];   // staged h_{t-1} lo, swizzled
    __shared__ float gtmp[8 * 16 * 17];              // gate pre-act transpose buffer
    __shared__ float hout[BM * 32];                  // this wg's new h slice (f32)
    __shared__ float xt[BM * 3];
    __shared__ float wlin[H_DIM];
    __shared__ float yred[NTHR];

    // ---- W_hh fragments (persistent in registers), bf16 hi/lo split ----
    // B-frag layout (16x16x32): lane holds B[k = kt*32 + (lane>>4)*8 + e][col = lane&15]
    short8 wfh[8], wfl[8];
    {
        const int c    = wave * 16 + cl;                       // 0..127
        const int wrow = (c & 3) * H_DIM + g * 32 + (c >> 2);  // gate*H + hidden
        const float* wr = W_hh + (size_t)wrow * H_DIM;
        #pragma unroll
        for (int kt = 0; kt < 8; ++kt) {
            const int k0 = kt * 32 + kgrp * 8;
            short8 hi8, lo8;
            #pragma unroll
            for (int e = 0; e < 8; ++e) {
                float w = wr[k0 + e];
                u16 hi = f2bf(w);
                u16 lo = f2bf(w - bf2f(hi));
                hi8[e] = (short)hi;
                lo8[e] = (short)lo;
            }
            wfh[kt] = hi8;
            wfl[kt] = lo8;
        }
    }

    // ---- per-lane constants for the pointwise phase: lane -> (m_p, jloc_p) ----
    const int m_p     = lane & 15;
    const int jq      = lane >> 4;
    const int jloc_p  = wave * 4 + jq;        // 0..31
    const int jglob_p = g * 32 + jloc_p;
    float bias4[4], wihr[4][3];
    #pragma unroll
    for (int gi = 0; gi < 4; ++gi) {
        const int row = gi * H_DIM + jglob_p;
        bias4[gi]  = b_ih[row] + b_hh[row];
        wihr[gi][0] = W_ih[row * 3 + 0];
        wihr[gi][1] = W_ih[row * 3 + 1];
        wihr[gi][2] = W_ih[row * 3 + 2];
    }
    if (tid < H_DIM) wlin[tid] = W_lin[tid];
    const float blin = b_lin[0];

    float cstate = 0.0f;   // c for (m_p, jloc_p)

    for (int t = 0; t < T_STEPS; ++t) {
        // stage x_t (independent of h, issued before the wait)
        if (tid < 48) {
            const int m = tid / 3, i = tid - m * 3;
            xt[m * 3 + i] = x[(size_t)(bg * BM + m) * (T_STEPS * 3) + t * 3 + i];
        }
        f32x4 acc0 = {0.f, 0.f, 0.f, 0.f};
        f32x4 acc1 = {0.f, 0.f, 0.f, 0.f};
        if (t > 0) {
            if (tid == 0) {
                const unsigned fidx = (unsigned)(t - 1) * NBG + (unsigned)bg;
                while (__hip_atomic_load(&cnt[fidx], __ATOMIC_ACQUIRE,
                                         __HIP_MEMORY_SCOPE_AGENT) < NCG)
                    __builtin_amdgcn_s_sleep(1);
            }
            __syncthreads();
            {   // stage full h_{t-1} pair global -> LDS (swizzled)
                const int slot = (t - 1) & 1;
                const int m = tid >> 5, kb = tid & 31;
                const size_t goff = ((size_t)(slot * NBG + bg) * BM + m) * H_DIM + kb * 8;
                const int didx = (m * H_DIM + kb * 8) ^ ((m & 7) << 3);
                *(short8*)&HShi[didx] = *(const short8*)&hb_hi[goff];
                *(short8*)&HSlo[didx] = *(const short8*)&hb_lo[goff];
            }
            __syncthreads();
            // gates[16, tile16] += h_{t-1} @ Wslice^T   (3-product bf16 split)
            // A-frag: lane holds A[m = lane&15][k = kt*32 + (lane>>4)*8 + e]
            #pragma unroll
            for (int kt = 0; kt < 8; ++kt) {
                const int aidx = (cl * H_DIM + kt * 32 + kgrp * 8) ^ ((cl & 7) << 3);
                const short8 ah = *(const short8*)&HShi[aidx];
                const short8 al = *(const short8*)&HSlo[aidx];
                acc0 = __builtin_amdgcn_mfma_f32_16x16x32_bf16(ah, wfh[kt], acc0, 0, 0, 0);
                acc1 = __builtin_amdgcn_mfma_f32_16x16x32_bf16(ah, wfl[kt], acc1, 0, 0, 0);
                acc0 = __builtin_amdgcn_mfma_f32_16x16x32_bf16(al, wfh[kt], acc0, 0, 0, 0);
            }
        } else {
            __syncthreads();   // make xt visible (no h_{-1})
        }
        // D layout: col = lane&15, row = (lane>>4)*4 + r  -> transpose via LDS
        #pragma unroll
        for (int r = 0; r < 4; ++r)
            gtmp[(wave * 16 + cl) * 17 + kgrp * 4 + r] = acc0[r] + acc1[r];
        __syncthreads();
        {   // pointwise: one (m_p, jloc_p) per lane
            const float x0 = xt[m_p * 3 + 0], x1 = xt[m_p * 3 + 1], x2 = xt[m_p * 3 + 2];
            float gv[4];
            #pragma unroll
            for (int gi = 0; gi < 4; ++gi) {
                float pre = gtmp[(wave * 16 + jq * 4 + gi) * 17 + m_p];
                pre += bias4[gi] + wihr[gi][0] * x0 + wihr[gi][1] * x1 + wihr[gi][2] * x2;
                gv[gi] = pre;
            }
            const float ig = sigmoid_f(gv[0]);
            const float fg = sigmoid_f(gv[1]);
            const float gg = tanh_f(gv[2]);
            const float og = sigmoid_f(gv[3]);
            cstate = fg * cstate + ig * gg;
            hout[m_p * 32 + jloc_p] = og * tanh_f(cstate);
        }
        __syncthreads();
        {   // publish own h_t slice (bf16 hi/lo pair), coalesced
            const int slot = t & 1;
            const int m = tid >> 5, j = tid & 31;
            const float h = hout[m * 32 + j];
            const u16 hi = f2bf(h);
            const u16 lo = f2bf(h - bf2f(hi));
            const size_t goff = ((size_t)(slot * NBG + bg) * BM + m) * H_DIM + g * 32 + j;
            hb_hi[goff] = hi;
            hb_lo[goff] = lo;
        }
        __syncthreads();   // drains all waves' stores (vmcnt 0) before release
        if (tid == 0)
            __hip_atomic_fetch_add(&cnt[(unsigned)t * NBG + (unsigned)bg], 1u,
                                   __ATOMIC_RELEASE, __HIP_MEMORY_SCOPE_AGENT);
        // Output projection for h_{t-1}: off the critical path (after release).
        if (g == 0 && t > 0) {
            const int m_y = tid & 15, seg = tid >> 4;
            float part = 0.f;
            #pragma unroll
            for (int e = 0; e < 8; ++e) {
                const int k = seg * 8 + e;
                const int idx = (m_y * H_DIM + k) ^ ((m_y & 7) << 3);
                part += (bf2f(HShi[idx]) + bf2f(HSlo[idx])) * wlin[k];
            }
            yred[tid] = part;
            __syncthreads();
            if (tid < BM) {
                float yv = blin;
                #pragma unroll
                for (int s = 0; s < 32; ++s) yv += yred[s * 16 + tid];
                out[(size_t)(bg * BM + tid) * T_STEPS + (t - 1)] = fmaxf(yv, 0.f);
            }
            __syncthreads();
        }
    }
    // final column y[:, T-1]
    if (g == 0) {
        if (tid == 0) {
            const unsigned fidx = (unsigned)(T_STEPS - 1) * NBG + (unsigned)bg;
            while (__hip_atomic_load(&cnt[fidx], __ATOMIC_ACQUIRE,
                                     __HIP_MEMORY_SCOPE_AGENT) < NCG)
                __builtin_amdgcn_s_sleep(1);
        }
        __syncthreads();
        {
            const int slot = (T_STEPS - 1) & 1;
            const int m = tid >> 5, kb = tid & 31;
            const size_t goff = ((size_t)(slot * NBG + bg) * BM + m) * H_DIM + kb * 8;
            const int didx = (m * H_DIM + kb * 8) ^ ((m & 7) << 3);
            *(short8*)&HShi[didx] = *(const short8*)&hb_hi[goff];
            *(short8*)&HSlo[didx] = *(const short8*)&hb_lo[goff];
        }
        __syncthreads();
        const int m_y = tid & 15, seg = tid >> 4;
        float part = 0.f;
        #pragma unroll
        for (int e = 0; e < 8; ++e) {
            const int k = seg * 8 + e;
            const int idx = (m_y * H_DIM + k) ^ ((m_y & 7) << 3);
            part += (bf2f(HShi[idx]) + bf2f(HSlo[idx])) * wlin[k];
        }
        yred[tid] = part;
        __syncthreads();
        if (tid < BM) {
            float yv = blin;
            #pragma unroll
            for (int s = 0; s < 32; ++s) yv += yred[s * 16 + tid];
            out[(size_t)(bg * BM + tid) * T_STEPS + (T_STEPS - 1)] = fmaxf(yv, 0.f);
        }
    }
}

extern "C" void kernel_launch(void* const* d_in, const int* in_sizes, int n_in,
                              void* d_out, int out_size, void* d_ws, size_t ws_size,
                              hipStream_t stream) {
    (void)in_sizes; (void)n_in; (void)out_size; (void)ws_size;
    const float* x     = (const float*)d_in[0];
    const float* W_ih  = (const float*)d_in[1];
    const float* W_hh  = (const float*)d_in[2];
    const float* b_ih  = (const float*)d_in[3];
    const float* b_hh  = (const float*)d_in[4];
    const float* W_lin = (const float*)d_in[5];
    const float* b_lin = (const float*)d_in[6];
    float* out = (float*)d_out;

    char* ws = (char*)d_ws;
    unsigned* cnt = (unsigned*)ws;                        // 512*16*4   = 32768 B
    u16* hb_hi = (u16*)(ws + 32768);                      // 2*16*16*256*2 = 262144 B
    u16* hb_lo = (u16*)(ws + 32768 + 262144);             // 262144 B

    hipMemsetAsync(cnt, 0, T_STEPS * NBG * sizeof(unsigned), stream);
    lstm_pipe_kernel<<<dim3(NBG * NCG), dim3(NTHR), 0, stream>>>(
        x, W_ih, W_hh, b_ih, b_hh, W_lin, b_lin, out, hb_hi, hb_lo, cnt);
}